// Round 1
// baseline (726.526 us; speedup 1.0000x reference)
//
#include <hip/hip_runtime.h>
#include <hip/hip_bf16.h>
#include <stdint.h>

// MoE: N=8192 tokens, H=1024, E=16 experts (top-2), I=512, shared IS=2048.
// Pipeline: router -> offsets/aux -> cvt(bf16) -> shared gemm1(fused silu) ->
// shared gemm2 (plain store, covers all out) -> expert gemm1 (gathered, fused)
// -> expert gemm2 (atomicAdd scatter). All bf16 MFMA 16x16x32, fp32 acc.

#define N_TOK 8192
#define HDIM 1024
#define NEXP 16
#define IEXP 512
#define ISH 2048

typedef __bf16 bf16x8 __attribute__((ext_vector_type(8)));
typedef float f32x4 __attribute__((ext_vector_type(4)));

// ---- ws layout (bytes) ----
#define OFF_XBF   ((size_t)0)            // 8192*1024*2   = 16,777,216
#define OFF_WSG   ((size_t)16777216)     // 2048*1024*2   =  4,194,304
#define OFF_WSU   ((size_t)20971520)
#define OFF_WSD   ((size_t)25165824)
#define OFF_SH    ((size_t)29360128)     // 8192*2048*2   = 33,554,432
#define OFF_HEXP  ((size_t)62914560)     // 16384*512*2   = 16,777,216
#define OFF_IDS   ((size_t)79691776)     // 16*8192*4     =    524,288
#define OFF_TW    ((size_t)80216064)     // 16*8192*4     =    524,288
#define OFF_META  ((size_t)80740352)     // 256 B: cnt[16]@0, off[17]@64, probs_sum[16]@144
#define OFF_SIG   ((size_t)80740608)     // 8192*4        =     32,768

static __device__ __forceinline__ unsigned short f2bf(float f) {
  unsigned int u = __float_as_uint(f);
  u += 0x7fffu + ((u >> 16) & 1u);
  return (unsigned short)(u >> 16);
}
static __device__ __forceinline__ int pack_bf2(float a, float b) {
  return (int)f2bf(a) | ((int)f2bf(b) << 16);
}

__global__ void cvt_kernel(const float* __restrict__ src,
                           unsigned short* __restrict__ dst, int n4) {
  int i = blockIdx.x * 256 + threadIdx.x;
  if (i >= n4) return;
  float4 v = ((const float4*)src)[i];
  uint2 o;
  o.x = (unsigned)pack_bf2(v.x, v.y);
  o.y = (unsigned)pack_bf2(v.z, v.w);
  ((uint2*)dst)[i] = o;
}

// ---- router: logits, softmax, top2, expert lists, aux accumulators, sigmoid gate
__global__ __launch_bounds__(256) void router_kernel(
    const float* __restrict__ X, const float* __restrict__ GW,
    const float* __restrict__ SEGW, int* __restrict__ cnt,
    float* __restrict__ probs_sum, int* __restrict__ ids,
    float* __restrict__ tw, float* __restrict__ sig) {
  int wid = threadIdx.x >> 6, lane = threadIdx.x & 63;
  int tok = blockIdx.x * 4 + wid;
  const float* xr = X + (size_t)tok * HDIM;
  float xv[16];
#pragma unroll
  for (int i = 0; i < 16; i++) xv[i] = xr[lane + 64 * i];
  float lg[17];
#pragma unroll
  for (int e = 0; e < 17; e++) {
    const float* wr = (e < 16) ? (GW + (size_t)e * HDIM) : SEGW;
    float p = 0.f;
#pragma unroll
    for (int i = 0; i < 16; i++) p += xv[i] * wr[lane + 64 * i];
#pragma unroll
    for (int off = 32; off >= 1; off >>= 1) p += __shfl_xor(p, off, 64);
    lg[e] = p;  // full sum in all lanes (butterfly)
  }
  float mx = lg[0];
#pragma unroll
  for (int e = 1; e < 16; e++) mx = fmaxf(mx, lg[e]);
  float pr[16], s = 0.f;
#pragma unroll
  for (int e = 0; e < 16; e++) { pr[e] = __expf(lg[e] - mx); s += pr[e]; }
  float inv_s = 1.f / s;
  float v1 = -1.f, v2 = -1.f; int i1 = 0, i2 = 0;
#pragma unroll
  for (int e = 0; e < 16; e++) {
    if (pr[e] > v1) { v2 = v1; i2 = i1; v1 = pr[e]; i1 = e; }
    else if (pr[e] > v2) { v2 = pr[e]; i2 = e; }
  }
  __shared__ float bps[16];
  if (threadIdx.x < 16) bps[threadIdx.x] = 0.f;
  __syncthreads();
  if (lane == 0) {
    float wsum = v1 + v2;
    int s1 = atomicAdd(&cnt[i1], 1);
    ids[i1 * N_TOK + s1] = tok; tw[i1 * N_TOK + s1] = v1 / wsum;
    int s2 = atomicAdd(&cnt[i2], 1);
    ids[i2 * N_TOK + s2] = tok; tw[i2 * N_TOK + s2] = v2 / wsum;
    sig[tok] = 1.f / (1.f + __expf(-lg[16]));
#pragma unroll
    for (int e = 0; e < 16; e++) atomicAdd(&bps[e], pr[e] * inv_s);
  }
  __syncthreads();
  if (threadIdx.x < 16) atomicAdd(&probs_sum[threadIdx.x], bps[threadIdx.x]);
}

__global__ void offs_aux_kernel(const int* __restrict__ cnt, int* __restrict__ off,
                                const float* __restrict__ probs_sum,
                                float* __restrict__ out_aux) {
  if (threadIdx.x == 0 && blockIdx.x == 0) {
    int run = 0; float aux = 0.f;
    for (int e = 0; e < NEXP; e++) {
      off[e] = run; run += cnt[e];
      aux += ((float)cnt[e] / (float)(N_TOK * 2)) * (probs_sum[e] / (float)N_TOK);
    }
    off[16] = run;
    *out_aux = (float)NEXP * aux;
  }
}

// ---- shared expert gemm1: H = silu(X@Wg^T) * (X@Wu^T), bf16 out [8192,2048]
__global__ __launch_bounds__(256) void shared_gemm1_kernel(
    const unsigned short* __restrict__ X, const unsigned short* __restrict__ Wg,
    const unsigned short* __restrict__ Wu, unsigned short* __restrict__ H) {
  __shared__ __align__(16) unsigned short As[128 * 32];
  __shared__ __align__(16) unsigned short Bs1[64 * 32];
  __shared__ __align__(16) unsigned short Bs2[64 * 32];
  int m0 = blockIdx.y * 128, n0 = blockIdx.x * 64;
  int t = threadIdx.x, lane = t & 63, w = t >> 6;
  int wm = (w & 1) * 64, wn = (w >> 1) * 32;
  int arow = t >> 2, akb = (t & 3) * 8;
  const unsigned short* ap0 = X + (size_t)(m0 + arow) * HDIM + akb;
  const unsigned short* ap1 = X + (size_t)(m0 + 64 + arow) * HDIM + akb;
  const unsigned short* bp1 = Wg + (size_t)(n0 + arow) * HDIM + akb;
  const unsigned short* bp2 = Wu + (size_t)(n0 + arow) * HDIM + akb;
  f32x4 z = {0.f, 0.f, 0.f, 0.f};
  f32x4 accg[4][2], accu[4][2];
#pragma unroll
  for (int i = 0; i < 4; i++)
#pragma unroll
    for (int j = 0; j < 2; j++) { accg[i][j] = z; accu[i][j] = z; }
  for (int k0 = 0; k0 < HDIM; k0 += 32) {
    int4 a0 = *(const int4*)(ap0 + k0);
    int4 a1 = *(const int4*)(ap1 + k0);
    int4 b1 = *(const int4*)(bp1 + k0);
    int4 b2 = *(const int4*)(bp2 + k0);
    __syncthreads();
    *(int4*)&As[arow * 32 + akb] = a0;
    *(int4*)&As[(64 + arow) * 32 + akb] = a1;
    *(int4*)&Bs1[arow * 32 + akb] = b1;
    *(int4*)&Bs2[arow * 32 + akb] = b2;
    __syncthreads();
    int fr = lane & 15, fc = (lane >> 4) * 8;
    bf16x8 af[4], bg[2], bu[2];
#pragma unroll
    for (int i = 0; i < 4; i++) af[i] = *(const bf16x8*)&As[(wm + i * 16 + fr) * 32 + fc];
#pragma unroll
    for (int j = 0; j < 2; j++) {
      bg[j] = *(const bf16x8*)&Bs1[(wn + j * 16 + fr) * 32 + fc];
      bu[j] = *(const bf16x8*)&Bs2[(wn + j * 16 + fr) * 32 + fc];
    }
#pragma unroll
    for (int i = 0; i < 4; i++)
#pragma unroll
      for (int j = 0; j < 2; j++) {
        accg[i][j] = __builtin_amdgcn_mfma_f32_16x16x32_bf16(af[i], bg[j], accg[i][j], 0, 0, 0);
        accu[i][j] = __builtin_amdgcn_mfma_f32_16x16x32_bf16(af[i], bu[j], accu[i][j], 0, 0, 0);
      }
  }
  int col = lane & 15, rq = (lane >> 4) * 4;
#pragma unroll
  for (int i = 0; i < 4; i++)
#pragma unroll
    for (int j = 0; j < 2; j++)
#pragma unroll
      for (int r = 0; r < 4; r++) {
        int mm = m0 + wm + i * 16 + rq + r;
        int nn = n0 + wn + j * 16 + col;
        float g = accg[i][j][r], u = accu[i][j][r];
        float h = g / (1.f + __expf(-g)) * u;
        H[(size_t)mm * ISH + nn] = f2bf(h);
      }
}

// ---- shared expert gemm2: Out = (H@Wd^T) * sig[token]   (plain fp32 store)
__global__ __launch_bounds__(256) void shared_gemm2_kernel(
    const unsigned short* __restrict__ H, const unsigned short* __restrict__ Wd,
    const float* __restrict__ sig, float* __restrict__ Out) {
  __shared__ __align__(16) unsigned short As[128 * 32];
  __shared__ __align__(16) unsigned short Bs[64 * 32];
  int m0 = blockIdx.y * 128, n0 = blockIdx.x * 64;
  int t = threadIdx.x, lane = t & 63, w = t >> 6;
  int wm = (w & 1) * 64, wn = (w >> 1) * 32;
  int arow = t >> 2, akb = (t & 3) * 8;
  const unsigned short* ap0 = H + (size_t)(m0 + arow) * ISH + akb;
  const unsigned short* ap1 = H + (size_t)(m0 + 64 + arow) * ISH + akb;
  const unsigned short* bp = Wd + (size_t)(n0 + arow) * ISH + akb;
  f32x4 z = {0.f, 0.f, 0.f, 0.f};
  f32x4 acc[4][2];
#pragma unroll
  for (int i = 0; i < 4; i++)
#pragma unroll
    for (int j = 0; j < 2; j++) acc[i][j] = z;
  for (int k0 = 0; k0 < ISH; k0 += 32) {
    int4 a0 = *(const int4*)(ap0 + k0);
    int4 a1 = *(const int4*)(ap1 + k0);
    int4 b0 = *(const int4*)(bp + k0);
    __syncthreads();
    *(int4*)&As[arow * 32 + akb] = a0;
    *(int4*)&As[(64 + arow) * 32 + akb] = a1;
    *(int4*)&Bs[arow * 32 + akb] = b0;
    __syncthreads();
    int fr = lane & 15, fc = (lane >> 4) * 8;
    bf16x8 af[4], bf[2];
#pragma unroll
    for (int i = 0; i < 4; i++) af[i] = *(const bf16x8*)&As[(wm + i * 16 + fr) * 32 + fc];
#pragma unroll
    for (int j = 0; j < 2; j++) bf[j] = *(const bf16x8*)&Bs[(wn + j * 16 + fr) * 32 + fc];
#pragma unroll
    for (int i = 0; i < 4; i++)
#pragma unroll
      for (int j = 0; j < 2; j++)
        acc[i][j] = __builtin_amdgcn_mfma_f32_16x16x32_bf16(af[i], bf[j], acc[i][j], 0, 0, 0);
  }
  int col = lane & 15, rq = (lane >> 4) * 4;
#pragma unroll
  for (int i = 0; i < 4; i++)
#pragma unroll
    for (int r = 0; r < 4; r++) {
      int mm = m0 + wm + i * 16 + rq + r;
      float sg = sig[mm];
#pragma unroll
      for (int j = 0; j < 2; j++) {
        int nn = n0 + wn + j * 16 + col;
        Out[(size_t)mm * HDIM + nn] = acc[i][j][r] * sg;
      }
    }
}

// ---- expert gemm1 (grouped, gathered A): Hexp = silu(g)*u, bf16 [16384,512]
__global__ __launch_bounds__(256) void exp_gemm1_kernel(
    const unsigned short* __restrict__ X, const float* __restrict__ WGU,
    const int* __restrict__ ids, const int* __restrict__ cnt,
    const int* __restrict__ off, unsigned short* __restrict__ Hexp) {
  int e = blockIdx.z;
  int ne = cnt[e];
  int m0 = blockIdx.y * 128;
  if (m0 >= ne) return;
  __shared__ __align__(16) unsigned short As[128 * 32];
  __shared__ __align__(16) unsigned short Bs1[64 * 32];
  __shared__ __align__(16) unsigned short Bs2[64 * 32];
  int n0 = blockIdx.x * 64;
  const int* eids = ids + e * N_TOK;
  int base = off[e];
  int t = threadIdx.x, lane = t & 63, w = t >> 6;
  int wm = (w & 1) * 64, wn = (w >> 1) * 32;
  int arow = t >> 2, akb = (t & 3) * 8;
  int s0 = m0 + arow, s1 = m0 + 64 + arow;
  int t0 = (s0 < ne) ? eids[s0] : 0;
  int t1 = (s1 < ne) ? eids[s1] : 0;
  const unsigned short* ap0 = X + (size_t)t0 * HDIM + akb;
  const unsigned short* ap1 = X + (size_t)t1 * HDIM + akb;
  const float* bpg = WGU + ((size_t)e * 1024 + n0 + arow) * HDIM + akb;
  const float* bpu = WGU + ((size_t)e * 1024 + 512 + n0 + arow) * HDIM + akb;
  f32x4 z = {0.f, 0.f, 0.f, 0.f};
  f32x4 accg[4][2], accu[4][2];
#pragma unroll
  for (int i = 0; i < 4; i++)
#pragma unroll
    for (int j = 0; j < 2; j++) { accg[i][j] = z; accu[i][j] = z; }
  for (int k0 = 0; k0 < HDIM; k0 += 32) {
    int4 a0 = *(const int4*)(ap0 + k0);
    int4 a1 = *(const int4*)(ap1 + k0);
    float4 g0 = *(const float4*)(bpg + k0);
    float4 g1 = *(const float4*)(bpg + k0 + 4);
    float4 u0 = *(const float4*)(bpu + k0);
    float4 u1 = *(const float4*)(bpu + k0 + 4);
    int4 b1, b2;
    b1.x = pack_bf2(g0.x, g0.y); b1.y = pack_bf2(g0.z, g0.w);
    b1.z = pack_bf2(g1.x, g1.y); b1.w = pack_bf2(g1.z, g1.w);
    b2.x = pack_bf2(u0.x, u0.y); b2.y = pack_bf2(u0.z, u0.w);
    b2.z = pack_bf2(u1.x, u1.y); b2.w = pack_bf2(u1.z, u1.w);
    __syncthreads();
    *(int4*)&As[arow * 32 + akb] = a0;
    *(int4*)&As[(64 + arow) * 32 + akb] = a1;
    *(int4*)&Bs1[arow * 32 + akb] = b1;
    *(int4*)&Bs2[arow * 32 + akb] = b2;
    __syncthreads();
    int fr = lane & 15, fc = (lane >> 4) * 8;
    bf16x8 af[4], bg[2], bu[2];
#pragma unroll
    for (int i = 0; i < 4; i++) af[i] = *(const bf16x8*)&As[(wm + i * 16 + fr) * 32 + fc];
#pragma unroll
    for (int j = 0; j < 2; j++) {
      bg[j] = *(const bf16x8*)&Bs1[(wn + j * 16 + fr) * 32 + fc];
      bu[j] = *(const bf16x8*)&Bs2[(wn + j * 16 + fr) * 32 + fc];
    }
#pragma unroll
    for (int i = 0; i < 4; i++)
#pragma unroll
      for (int j = 0; j < 2; j++) {
        accg[i][j] = __builtin_amdgcn_mfma_f32_16x16x32_bf16(af[i], bg[j], accg[i][j], 0, 0, 0);
        accu[i][j] = __builtin_amdgcn_mfma_f32_16x16x32_bf16(af[i], bu[j], accu[i][j], 0, 0, 0);
      }
  }
  int col = lane & 15, rq = (lane >> 4) * 4;
#pragma unroll
  for (int i = 0; i < 4; i++)
#pragma unroll
    for (int j = 0; j < 2; j++)
#pragma unroll
      for (int r = 0; r < 4; r++) {
        int slot = m0 + wm + i * 16 + rq + r;
        if (slot < ne) {
          int nn = n0 + wn + j * 16 + col;
          float g = accg[i][j][r], u = accu[i][j][r];
          float h = g / (1.f + __expf(-g)) * u;
          Hexp[(size_t)(base + slot) * IEXP + nn] = f2bf(h);
        }
      }
}

// ---- expert gemm2 (grouped): atomicAdd(Out, tw * (Hexp@Wd^T))
__global__ __launch_bounds__(256) void exp_gemm2_kernel(
    const unsigned short* __restrict__ Hexp, const float* __restrict__ WD,
    const int* __restrict__ ids, const float* __restrict__ tw,
    const int* __restrict__ cnt, const int* __restrict__ off,
    float* __restrict__ Out) {
  int e = blockIdx.z;
  int ne = cnt[e];
  int m0 = blockIdx.y * 128;
  if (m0 >= ne) return;
  __shared__ __align__(16) unsigned short As[128 * 32];
  __shared__ __align__(16) unsigned short Bs[64 * 32];
  int n0 = blockIdx.x * 64;
  const int* eids = ids + e * N_TOK;
  const float* etw = tw + e * N_TOK;
  int base = off[e];
  int t = threadIdx.x, lane = t & 63, w = t >> 6;
  int wm = (w & 1) * 64, wn = (w >> 1) * 32;
  int arow = t >> 2, akb = (t & 3) * 8;
  int ra0 = base + m0 + arow;        if (ra0 > 16383) ra0 = 16383;
  int ra1 = base + m0 + 64 + arow;   if (ra1 > 16383) ra1 = 16383;
  const unsigned short* ap0 = Hexp + (size_t)ra0 * IEXP + akb;
  const unsigned short* ap1 = Hexp + (size_t)ra1 * IEXP + akb;
  const float* bp = WD + ((size_t)e * HDIM + n0 + arow) * IEXP + akb;
  f32x4 z = {0.f, 0.f, 0.f, 0.f};
  f32x4 acc[4][2];
#pragma unroll
  for (int i = 0; i < 4; i++)
#pragma unroll
    for (int j = 0; j < 2; j++) acc[i][j] = z;
  for (int k0 = 0; k0 < IEXP; k0 += 32) {
    int4 a0 = *(const int4*)(ap0 + k0);
    int4 a1 = *(const int4*)(ap1 + k0);
    float4 d0 = *(const float4*)(bp + k0);
    float4 d1 = *(const float4*)(bp + k0 + 4);
    int4 b0;
    b0.x = pack_bf2(d0.x, d0.y); b0.y = pack_bf2(d0.z, d0.w);
    b0.z = pack_bf2(d1.x, d1.y); b0.w = pack_bf2(d1.z, d1.w);
    __syncthreads();
    *(int4*)&As[arow * 32 + akb] = a0;
    *(int4*)&As[(64 + arow) * 32 + akb] = a1;
    *(int4*)&Bs[arow * 32 + akb] = b0;
    __syncthreads();
    int fr = lane & 15, fc = (lane >> 4) * 8;
    bf16x8 af[4], bf[2];
#pragma unroll
    for (int i = 0; i < 4; i++) af[i] = *(const bf16x8*)&As[(wm + i * 16 + fr) * 32 + fc];
#pragma unroll
    for (int j = 0; j < 2; j++) bf[j] = *(const bf16x8*)&Bs[(wn + j * 16 + fr) * 32 + fc];
#pragma unroll
    for (int i = 0; i < 4; i++)
#pragma unroll
      for (int j = 0; j < 2; j++)
        acc[i][j] = __builtin_amdgcn_mfma_f32_16x16x32_bf16(af[i], bf[j], acc[i][j], 0, 0, 0);
  }
  int col = lane & 15, rq = (lane >> 4) * 4;
#pragma unroll
  for (int i = 0; i < 4; i++)
#pragma unroll
    for (int r = 0; r < 4; r++) {
      int slot = m0 + wm + i * 16 + rq + r;
      if (slot < ne) {
        int tok = eids[slot];
        float wgt = etw[slot];
#pragma unroll
        for (int j = 0; j < 2; j++) {
          int nn = n0 + wn + j * 16 + col;
          atomicAdd(&Out[(size_t)tok * HDIM + nn], acc[i][j][r] * wgt);
        }
      }
    }
}

extern "C" void kernel_launch(void* const* d_in, const int* in_sizes, int n_in,
                              void* d_out, int out_size, void* d_ws, size_t ws_size,
                              hipStream_t stream) {
  const float* X   = (const float*)d_in[0];
  const float* GW  = (const float*)d_in[1];
  const float* WGU = (const float*)d_in[2];
  const float* WDN = (const float*)d_in[3];
  const float* WSG = (const float*)d_in[4];
  const float* WSU = (const float*)d_in[5];
  const float* WSD = (const float*)d_in[6];
  const float* SEGW = (const float*)d_in[7];
  float* Out = (float*)d_out;
  char* ws = (char*)d_ws;

  unsigned short* xbf  = (unsigned short*)(ws + OFF_XBF);
  unsigned short* wsg  = (unsigned short*)(ws + OFF_WSG);
  unsigned short* wsu  = (unsigned short*)(ws + OFF_WSU);
  unsigned short* wsd  = (unsigned short*)(ws + OFF_WSD);
  unsigned short* sh   = (unsigned short*)(ws + OFF_SH);
  unsigned short* hexp = (unsigned short*)(ws + OFF_HEXP);
  int*   ids  = (int*)(ws + OFF_IDS);
  float* tw   = (float*)(ws + OFF_TW);
  int*   cnt  = (int*)(ws + OFF_META);
  int*   off  = (int*)(ws + OFF_META + 64);
  float* pps  = (float*)(ws + OFF_META + 144);
  float* sig  = (float*)(ws + OFF_SIG);

  hipMemsetAsync(ws + OFF_META, 0, 256, stream);

  // f32 -> bf16 converts
  {
    int n4;
    n4 = (N_TOK * HDIM) / 4;
    cvt_kernel<<<(n4 + 255) / 256, 256, 0, stream>>>(X, xbf, n4);
    n4 = (ISH * HDIM) / 4;
    cvt_kernel<<<(n4 + 255) / 256, 256, 0, stream>>>(WSG, wsg, n4);
    cvt_kernel<<<(n4 + 255) / 256, 256, 0, stream>>>(WSU, wsu, n4);
    n4 = (HDIM * ISH) / 4;
    cvt_kernel<<<(n4 + 255) / 256, 256, 0, stream>>>(WSD, wsd, n4);
  }

  router_kernel<<<N_TOK / 4, 256, 0, stream>>>(X, GW, SEGW, cnt, pps, ids, tw, sig);
  offs_aux_kernel<<<1, 64, 0, stream>>>(cnt, off, pps, Out + (size_t)N_TOK * HDIM);

  // shared expert
  shared_gemm1_kernel<<<dim3(ISH / 64, N_TOK / 128), 256, 0, stream>>>(xbf, wsg, wsu, sh);
  shared_gemm2_kernel<<<dim3(HDIM / 64, N_TOK / 128), 256, 0, stream>>>(sh, wsd, sig, Out);

  // routed experts (after shared gemm2's plain store; atomics accumulate on top)
  exp_gemm1_kernel<<<dim3(IEXP / 64, N_TOK / 128, NEXP), 256, 0, stream>>>(
      xbf, WGU, ids, cnt, off, hexp);
  exp_gemm2_kernel<<<dim3(HDIM / 64, N_TOK / 128, NEXP), 256, 0, stream>>>(
      hexp, WDN, ids, tw, cnt, off, Out);
}

// Round 2
// 541.276 us; speedup vs baseline: 1.3422x; 1.3422x over previous
//
#include <hip/hip_runtime.h>
#include <hip/hip_bf16.h>
#include <stdint.h>

// MoE: N=8192 tokens, H=1024, E=16 experts (top-2), I=512, shared IS=2048.
// R2: router split (block-aggregated atomics: 49k global atomics -> 1k),
//     global_load_lds width=16 staging in all GEMMs (m97 structure),
//     shared gemm2 upgraded to 128x128 tile.

#define N_TOK 8192
#define HDIM 1024
#define NEXP 16
#define IEXP 512
#define ISH 2048

typedef __bf16 bf16x8 __attribute__((ext_vector_type(8)));
typedef float f32x4 __attribute__((ext_vector_type(4)));

// ---- ws layout (bytes) ----
#define OFF_XBF   ((size_t)0)            // 8192*1024*2
#define OFF_WSG   ((size_t)16777216)     // 2048*1024*2
#define OFF_WSU   ((size_t)20971520)
#define OFF_WSD   ((size_t)25165824)
#define OFF_SH    ((size_t)29360128)     // 8192*2048*2
#define OFF_HEXP  ((size_t)62914560)     // 16384*512*2
#define OFF_IDS   ((size_t)79691776)     // 16*8192*4
#define OFF_TW    ((size_t)80216064)     // 16*8192*4
#define OFF_META  ((size_t)80740352)     // cnt[16]@0, off[17]@64, probs_sum[16]@144
#define OFF_SIG   ((size_t)80740608)     // 8192*4
#define OFF_LG    ((size_t)80773376)     // 8192*32*4 = 1,048,576 logits (padded)

static __device__ __forceinline__ unsigned short f2bf(float f) {
  unsigned int u = __float_as_uint(f);
  u += 0x7fffu + ((u >> 16) & 1u);
  return (unsigned short)(u >> 16);
}
static __device__ __forceinline__ int pack_bf2(float a, float b) {
  return (int)f2bf(a) | ((int)f2bf(b) << 16);
}
// async 16B global->LDS (wave-uniform base + lane*16; our layouts are t*16-contiguous)
static __device__ __forceinline__ void gl_lds16(const void* g, void* l) {
  __builtin_amdgcn_global_load_lds(
      (const __attribute__((address_space(1))) unsigned int*)g,
      (__attribute__((address_space(3))) unsigned int*)l, 16, 0, 0);
}

__global__ void cvt_kernel(const float* __restrict__ src,
                           unsigned short* __restrict__ dst, int n4) {
  int i = blockIdx.x * 256 + threadIdx.x;
  if (i >= n4) return;
  float4 v = ((const float4*)src)[i];
  uint2 o;
  o.x = (unsigned)pack_bf2(v.x, v.y);
  o.y = (unsigned)pack_bf2(v.z, v.w);
  ((uint2*)dst)[i] = o;
}

// ---- phase 1: logits only (wave per token, butterfly reduce, no atomics)
__global__ __launch_bounds__(256) void logits_kernel(
    const float* __restrict__ X, const float* __restrict__ GW,
    const float* __restrict__ SEGW, float* __restrict__ LG) {
  int wid = threadIdx.x >> 6, lane = threadIdx.x & 63;
  int tok = blockIdx.x * 4 + wid;
  const float* xr = X + (size_t)tok * HDIM;
  float xv[16];
#pragma unroll
  for (int i = 0; i < 16; i++) xv[i] = xr[lane + 64 * i];
  float myv = 0.f;
#pragma unroll
  for (int e = 0; e < 17; e++) {
    const float* wr = (e < 16) ? (GW + (size_t)e * HDIM) : SEGW;
    float p = 0.f;
#pragma unroll
    for (int i = 0; i < 16; i++) p += xv[i] * wr[lane + 64 * i];
#pragma unroll
    for (int off = 32; off >= 1; off >>= 1) p += __shfl_xor(p, off, 64);
    if (lane == e) myv = p;
  }
  if (lane < 17) LG[(size_t)tok * 32 + lane] = myv;
}

// ---- phase 2: softmax/top2/scatter with block-local aggregation
__global__ __launch_bounds__(256) void route_kernel(
    const float* __restrict__ LG, int* __restrict__ cnt,
    float* __restrict__ pps, int* __restrict__ ids,
    float* __restrict__ tw, float* __restrict__ sig) {
  __shared__ int lcnt[16];
  __shared__ int lbase[16];
  __shared__ float lps[16];
  int tid = threadIdx.x;
  int tok = blockIdx.x * 256 + tid;
  if (tid < 16) { lcnt[tid] = 0; lps[tid] = 0.f; }
  __syncthreads();
  const float4* row = (const float4*)(LG + (size_t)tok * 32);
  float4 v0 = row[0], v1 = row[1], v2 = row[2], v3 = row[3];
  float g16 = row[4].x;
  float lg[16] = {v0.x, v0.y, v0.z, v0.w, v1.x, v1.y, v1.z, v1.w,
                  v2.x, v2.y, v2.z, v2.w, v3.x, v3.y, v3.z, v3.w};
  float mx = lg[0];
#pragma unroll
  for (int e = 1; e < 16; e++) mx = fmaxf(mx, lg[e]);
  float pr[16], s = 0.f;
#pragma unroll
  for (int e = 0; e < 16; e++) { pr[e] = __expf(lg[e] - mx); s += pr[e]; }
  float inv_s = 1.f / s;
  float p1 = -1.f, p2 = -1.f; int i1 = 0, i2 = 0;
#pragma unroll
  for (int e = 0; e < 16; e++) {
    if (pr[e] > p1) { p2 = p1; i2 = i1; p1 = pr[e]; i1 = e; }
    else if (pr[e] > p2) { p2 = pr[e]; i2 = e; }
  }
  float wsum = p1 + p2;
  int s1 = atomicAdd(&lcnt[i1], 1);
  int s2 = atomicAdd(&lcnt[i2], 1);
#pragma unroll
  for (int e = 0; e < 16; e++) atomicAdd(&lps[e], pr[e] * inv_s);
  sig[tok] = 1.f / (1.f + __expf(-g16));
  __syncthreads();
  if (tid < 16) {
    lbase[tid] = atomicAdd(&cnt[tid], lcnt[tid]);
    atomicAdd(&pps[tid], lps[tid]);
  }
  __syncthreads();
  int d1 = i1 * N_TOK + lbase[i1] + s1;
  int d2 = i2 * N_TOK + lbase[i2] + s2;
  ids[d1] = tok; tw[d1] = p1 / wsum;
  ids[d2] = tok; tw[d2] = p2 / wsum;
}

__global__ void offs_aux_kernel(const int* __restrict__ cnt, int* __restrict__ off,
                                const float* __restrict__ probs_sum,
                                float* __restrict__ out_aux) {
  if (threadIdx.x == 0 && blockIdx.x == 0) {
    int run = 0; float aux = 0.f;
    for (int e = 0; e < NEXP; e++) {
      off[e] = run; run += cnt[e];
      aux += ((float)cnt[e] / (float)(N_TOK * 2)) * (probs_sum[e] / (float)N_TOK);
    }
    off[16] = run;
    *out_aux = (float)NEXP * aux;
  }
}

// ---- shared gemm1: H = silu(X@Wg^T) * (X@Wu^T), bf16 out [8192,2048]
// 128x64 tile, async staging
__global__ __launch_bounds__(256) void shared_gemm1_kernel(
    const unsigned short* __restrict__ X, const unsigned short* __restrict__ Wg,
    const unsigned short* __restrict__ Wu, unsigned short* __restrict__ H) {
  __shared__ __align__(16) unsigned short As[128 * 32];
  __shared__ __align__(16) unsigned short Bs1[64 * 32];
  __shared__ __align__(16) unsigned short Bs2[64 * 32];
  int m0 = blockIdx.y * 128, n0 = blockIdx.x * 64;
  int t = threadIdx.x, lane = t & 63, w = t >> 6;
  int wm = (w & 1) * 64, wn = (w >> 1) * 32;
  int arow = t >> 2, akb = (t & 3) * 8;
  const unsigned short* ap0 = X + (size_t)(m0 + arow) * HDIM + akb;
  const unsigned short* ap1 = X + (size_t)(m0 + 64 + arow) * HDIM + akb;
  const unsigned short* bp1 = Wg + (size_t)(n0 + arow) * HDIM + akb;
  const unsigned short* bp2 = Wu + (size_t)(n0 + arow) * HDIM + akb;
  f32x4 z = {0.f, 0.f, 0.f, 0.f};
  f32x4 accg[4][2], accu[4][2];
#pragma unroll
  for (int i = 0; i < 4; i++)
#pragma unroll
    for (int j = 0; j < 2; j++) { accg[i][j] = z; accu[i][j] = z; }
  for (int k0 = 0; k0 < HDIM; k0 += 32) {
    __syncthreads();
    gl_lds16(ap0 + k0, &As[t * 8]);
    gl_lds16(ap1 + k0, &As[2048 + t * 8]);
    gl_lds16(bp1 + k0, &Bs1[t * 8]);
    gl_lds16(bp2 + k0, &Bs2[t * 8]);
    __syncthreads();
    int fr = lane & 15, fc = (lane >> 4) * 8;
    bf16x8 af[4], bg[2], bu[2];
#pragma unroll
    for (int i = 0; i < 4; i++) af[i] = *(const bf16x8*)&As[(wm + i * 16 + fr) * 32 + fc];
#pragma unroll
    for (int j = 0; j < 2; j++) {
      bg[j] = *(const bf16x8*)&Bs1[(wn + j * 16 + fr) * 32 + fc];
      bu[j] = *(const bf16x8*)&Bs2[(wn + j * 16 + fr) * 32 + fc];
    }
#pragma unroll
    for (int i = 0; i < 4; i++)
#pragma unroll
      for (int j = 0; j < 2; j++) {
        accg[i][j] = __builtin_amdgcn_mfma_f32_16x16x32_bf16(af[i], bg[j], accg[i][j], 0, 0, 0);
        accu[i][j] = __builtin_amdgcn_mfma_f32_16x16x32_bf16(af[i], bu[j], accu[i][j], 0, 0, 0);
      }
  }
  int col = lane & 15, rq = (lane >> 4) * 4;
#pragma unroll
  for (int i = 0; i < 4; i++)
#pragma unroll
    for (int j = 0; j < 2; j++)
#pragma unroll
      for (int r = 0; r < 4; r++) {
        int mm = m0 + wm + i * 16 + rq + r;
        int nn = n0 + wn + j * 16 + col;
        float g = accg[i][j][r], u = accu[i][j][r];
        float h = g / (1.f + __expf(-g)) * u;
        H[(size_t)mm * ISH + nn] = f2bf(h);
      }
}

// ---- shared gemm2: Out = (H@Wd^T) * sig[token]; m97-style 128x128 tile
__global__ __launch_bounds__(256) void shared_gemm2_kernel(
    const unsigned short* __restrict__ H, const unsigned short* __restrict__ Wd,
    const float* __restrict__ sig, float* __restrict__ Out) {
  __shared__ __align__(16) unsigned short As[128 * 32];
  __shared__ __align__(16) unsigned short Bs[128 * 32];
  int m0 = blockIdx.y * 128, n0 = blockIdx.x * 128;
  int t = threadIdx.x, lane = t & 63, w = t >> 6;
  int wm = (w & 1) * 64, wn = (w >> 1) * 64;
  int arow = t >> 2, akb = (t & 3) * 8;
  const unsigned short* apA0 = H + (size_t)(m0 + arow) * ISH + akb;
  const unsigned short* apA1 = H + (size_t)(m0 + 64 + arow) * ISH + akb;
  const unsigned short* apB0 = Wd + (size_t)(n0 + arow) * ISH + akb;
  const unsigned short* apB1 = Wd + (size_t)(n0 + 64 + arow) * ISH + akb;
  f32x4 z = {0.f, 0.f, 0.f, 0.f};
  f32x4 acc[4][4];
#pragma unroll
  for (int i = 0; i < 4; i++)
#pragma unroll
    for (int j = 0; j < 4; j++) acc[i][j] = z;
  for (int k0 = 0; k0 < ISH; k0 += 32) {
    __syncthreads();
    gl_lds16(apA0 + k0, &As[t * 8]);
    gl_lds16(apA1 + k0, &As[2048 + t * 8]);
    gl_lds16(apB0 + k0, &Bs[t * 8]);
    gl_lds16(apB1 + k0, &Bs[2048 + t * 8]);
    __syncthreads();
    int fr = lane & 15, fc = (lane >> 4) * 8;
    bf16x8 af[4], bfr[4];
#pragma unroll
    for (int i = 0; i < 4; i++) {
      af[i] = *(const bf16x8*)&As[(wm + i * 16 + fr) * 32 + fc];
      bfr[i] = *(const bf16x8*)&Bs[(wn + i * 16 + fr) * 32 + fc];
    }
#pragma unroll
    for (int i = 0; i < 4; i++)
#pragma unroll
      for (int j = 0; j < 4; j++)
        acc[i][j] = __builtin_amdgcn_mfma_f32_16x16x32_bf16(af[i], bfr[j], acc[i][j], 0, 0, 0);
  }
  int col = lane & 15, rq = (lane >> 4) * 4;
#pragma unroll
  for (int i = 0; i < 4; i++)
#pragma unroll
    for (int r = 0; r < 4; r++) {
      int mm = m0 + wm + i * 16 + rq + r;
      float sg = sig[mm];
#pragma unroll
      for (int j = 0; j < 4; j++) {
        int nn = n0 + wn + j * 16 + col;
        Out[(size_t)mm * HDIM + nn] = acc[i][j][r] * sg;
      }
    }
}

// ---- expert gemm1 (grouped, gathered A): Hexp = silu(g)*u
__global__ __launch_bounds__(256) void exp_gemm1_kernel(
    const unsigned short* __restrict__ X, const float* __restrict__ WGU,
    const int* __restrict__ ids, const int* __restrict__ cnt,
    const int* __restrict__ off, unsigned short* __restrict__ Hexp) {
  int e = blockIdx.z;
  int ne = cnt[e];
  int m0 = blockIdx.y * 128;
  if (m0 >= ne) return;
  __shared__ __align__(16) unsigned short As[128 * 32];
  __shared__ __align__(16) unsigned short Bs1[64 * 32];
  __shared__ __align__(16) unsigned short Bs2[64 * 32];
  int n0 = blockIdx.x * 64;
  const int* eids = ids + e * N_TOK;
  int base = off[e];
  int t = threadIdx.x, lane = t & 63, w = t >> 6;
  int wm = (w & 1) * 64, wn = (w >> 1) * 32;
  int arow = t >> 2, akb = (t & 3) * 8;
  int s0 = m0 + arow, s1 = m0 + 64 + arow;
  int t0 = (s0 < ne) ? eids[s0] : 0;
  int t1 = (s1 < ne) ? eids[s1] : 0;
  const unsigned short* ap0 = X + (size_t)t0 * HDIM + akb;
  const unsigned short* ap1 = X + (size_t)t1 * HDIM + akb;
  const float* bpg = WGU + ((size_t)e * 1024 + n0 + arow) * HDIM + akb;
  const float* bpu = WGU + ((size_t)e * 1024 + 512 + n0 + arow) * HDIM + akb;
  f32x4 z = {0.f, 0.f, 0.f, 0.f};
  f32x4 accg[4][2], accu[4][2];
#pragma unroll
  for (int i = 0; i < 4; i++)
#pragma unroll
    for (int j = 0; j < 2; j++) { accg[i][j] = z; accu[i][j] = z; }
  for (int k0 = 0; k0 < HDIM; k0 += 32) {
    float4 g0 = *(const float4*)(bpg + k0);
    float4 g1 = *(const float4*)(bpg + k0 + 4);
    float4 u0 = *(const float4*)(bpu + k0);
    float4 u1 = *(const float4*)(bpu + k0 + 4);
    int4 b1, b2;
    b1.x = pack_bf2(g0.x, g0.y); b1.y = pack_bf2(g0.z, g0.w);
    b1.z = pack_bf2(g1.x, g1.y); b1.w = pack_bf2(g1.z, g1.w);
    b2.x = pack_bf2(u0.x, u0.y); b2.y = pack_bf2(u0.z, u0.w);
    b2.z = pack_bf2(u1.x, u1.y); b2.w = pack_bf2(u1.z, u1.w);
    __syncthreads();
    gl_lds16(ap0 + k0, &As[t * 8]);
    gl_lds16(ap1 + k0, &As[2048 + t * 8]);
    *(int4*)&Bs1[arow * 32 + akb] = b1;
    *(int4*)&Bs2[arow * 32 + akb] = b2;
    __syncthreads();
    int fr = lane & 15, fc = (lane >> 4) * 8;
    bf16x8 af[4], bg[2], bu[2];
#pragma unroll
    for (int i = 0; i < 4; i++) af[i] = *(const bf16x8*)&As[(wm + i * 16 + fr) * 32 + fc];
#pragma unroll
    for (int j = 0; j < 2; j++) {
      bg[j] = *(const bf16x8*)&Bs1[(wn + j * 16 + fr) * 32 + fc];
      bu[j] = *(const bf16x8*)&Bs2[(wn + j * 16 + fr) * 32 + fc];
    }
#pragma unroll
    for (int i = 0; i < 4; i++)
#pragma unroll
      for (int j = 0; j < 2; j++) {
        accg[i][j] = __builtin_amdgcn_mfma_f32_16x16x32_bf16(af[i], bg[j], accg[i][j], 0, 0, 0);
        accu[i][j] = __builtin_amdgcn_mfma_f32_16x16x32_bf16(af[i], bu[j], accu[i][j], 0, 0, 0);
      }
  }
  int col = lane & 15, rq = (lane >> 4) * 4;
#pragma unroll
  for (int i = 0; i < 4; i++)
#pragma unroll
    for (int j = 0; j < 2; j++)
#pragma unroll
      for (int r = 0; r < 4; r++) {
        int slot = m0 + wm + i * 16 + rq + r;
        if (slot < ne) {
          int nn = n0 + wn + j * 16 + col;
          float g = accg[i][j][r], u = accu[i][j][r];
          float h = g / (1.f + __expf(-g)) * u;
          Hexp[(size_t)(base + slot) * IEXP + nn] = f2bf(h);
        }
      }
}

// ---- expert gemm2 (grouped): atomicAdd(Out, tw * (Hexp@Wd^T))
__global__ __launch_bounds__(256) void exp_gemm2_kernel(
    const unsigned short* __restrict__ Hexp, const float* __restrict__ WD,
    const int* __restrict__ ids, const float* __restrict__ tw,
    const int* __restrict__ cnt, const int* __restrict__ off,
    float* __restrict__ Out) {
  int e = blockIdx.z;
  int ne = cnt[e];
  int m0 = blockIdx.y * 128;
  if (m0 >= ne) return;
  __shared__ __align__(16) unsigned short As[128 * 32];
  __shared__ __align__(16) unsigned short Bs[64 * 32];
  int n0 = blockIdx.x * 64;
  const int* eids = ids + e * N_TOK;
  const float* etw = tw + e * N_TOK;
  int base = off[e];
  int t = threadIdx.x, lane = t & 63, w = t >> 6;
  int wm = (w & 1) * 64, wn = (w >> 1) * 32;
  int arow = t >> 2, akb = (t & 3) * 8;
  int ra0 = base + m0 + arow;        if (ra0 > 16383) ra0 = 16383;
  int ra1 = base + m0 + 64 + arow;   if (ra1 > 16383) ra1 = 16383;
  const unsigned short* ap0 = Hexp + (size_t)ra0 * IEXP + akb;
  const unsigned short* ap1 = Hexp + (size_t)ra1 * IEXP + akb;
  const float* bp = WD + ((size_t)e * HDIM + n0 + arow) * IEXP + akb;
  f32x4 z = {0.f, 0.f, 0.f, 0.f};
  f32x4 acc[4][2];
#pragma unroll
  for (int i = 0; i < 4; i++)
#pragma unroll
    for (int j = 0; j < 2; j++) acc[i][j] = z;
  for (int k0 = 0; k0 < IEXP; k0 += 32) {
    float4 d0 = *(const float4*)(bp + k0);
    float4 d1 = *(const float4*)(bp + k0 + 4);
    int4 b0;
    b0.x = pack_bf2(d0.x, d0.y); b0.y = pack_bf2(d0.z, d0.w);
    b0.z = pack_bf2(d1.x, d1.y); b0.w = pack_bf2(d1.z, d1.w);
    __syncthreads();
    gl_lds16(ap0 + k0, &As[t * 8]);
    gl_lds16(ap1 + k0, &As[2048 + t * 8]);
    *(int4*)&Bs[arow * 32 + akb] = b0;
    __syncthreads();
    int fr = lane & 15, fc = (lane >> 4) * 8;
    bf16x8 af[4], bfr[2];
#pragma unroll
    for (int i = 0; i < 4; i++) af[i] = *(const bf16x8*)&As[(wm + i * 16 + fr) * 32 + fc];
#pragma unroll
    for (int j = 0; j < 2; j++) bfr[j] = *(const bf16x8*)&Bs[(wn + j * 16 + fr) * 32 + fc];
#pragma unroll
    for (int i = 0; i < 4; i++)
#pragma unroll
      for (int j = 0; j < 2; j++)
        acc[i][j] = __builtin_amdgcn_mfma_f32_16x16x32_bf16(af[i], bfr[j], acc[i][j], 0, 0, 0);
  }
  int col = lane & 15, rq = (lane >> 4) * 4;
#pragma unroll
  for (int i = 0; i < 4; i++)
#pragma unroll
    for (int r = 0; r < 4; r++) {
      int slot = m0 + wm + i * 16 + rq + r;
      if (slot < ne) {
        int tok = eids[slot];
        float wgt = etw[slot];
#pragma unroll
        for (int j = 0; j < 2; j++) {
          int nn = n0 + wn + j * 16 + col;
          atomicAdd(&Out[(size_t)tok * HDIM + nn], acc[i][j][r] * wgt);
        }
      }
    }
}

extern "C" void kernel_launch(void* const* d_in, const int* in_sizes, int n_in,
                              void* d_out, int out_size, void* d_ws, size_t ws_size,
                              hipStream_t stream) {
  const float* X   = (const float*)d_in[0];
  const float* GW  = (const float*)d_in[1];
  const float* WGU = (const float*)d_in[2];
  const float* WDN = (const float*)d_in[3];
  const float* WSG = (const float*)d_in[4];
  const float* WSU = (const float*)d_in[5];
  const float* WSD = (const float*)d_in[6];
  const float* SEGW = (const float*)d_in[7];
  float* Out = (float*)d_out;
  char* ws = (char*)d_ws;

  unsigned short* xbf  = (unsigned short*)(ws + OFF_XBF);
  unsigned short* wsg  = (unsigned short*)(ws + OFF_WSG);
  unsigned short* wsu  = (unsigned short*)(ws + OFF_WSU);
  unsigned short* wsd  = (unsigned short*)(ws + OFF_WSD);
  unsigned short* sh   = (unsigned short*)(ws + OFF_SH);
  unsigned short* hexp = (unsigned short*)(ws + OFF_HEXP);
  int*   ids  = (int*)(ws + OFF_IDS);
  float* tw   = (float*)(ws + OFF_TW);
  int*   cnt  = (int*)(ws + OFF_META);
  int*   off  = (int*)(ws + OFF_META + 64);
  float* pps  = (float*)(ws + OFF_META + 144);
  float* sig  = (float*)(ws + OFF_SIG);
  float* lg   = (float*)(ws + OFF_LG);

  hipMemsetAsync(ws + OFF_META, 0, 256, stream);

  // f32 -> bf16 converts
  {
    int n4;
    n4 = (N_TOK * HDIM) / 4;
    cvt_kernel<<<(n4 + 255) / 256, 256, 0, stream>>>(X, xbf, n4);
    n4 = (ISH * HDIM) / 4;
    cvt_kernel<<<(n4 + 255) / 256, 256, 0, stream>>>(WSG, wsg, n4);
    cvt_kernel<<<(n4 + 255) / 256, 256, 0, stream>>>(WSU, wsu, n4);
    n4 = (HDIM * ISH) / 4;
    cvt_kernel<<<(n4 + 255) / 256, 256, 0, stream>>>(WSD, wsd, n4);
  }

  logits_kernel<<<N_TOK / 4, 256, 0, stream>>>(X, GW, SEGW, lg);
  route_kernel<<<N_TOK / 256, 256, 0, stream>>>(lg, cnt, pps, ids, tw, sig);
  offs_aux_kernel<<<1, 64, 0, stream>>>(cnt, off, pps, Out + (size_t)N_TOK * HDIM);

  // shared expert
  shared_gemm1_kernel<<<dim3(ISH / 64, N_TOK / 128), 256, 0, stream>>>(xbf, wsg, wsu, sh);
  shared_gemm2_kernel<<<dim3(HDIM / 128, N_TOK / 128), 256, 0, stream>>>(sh, wsd, sig, Out);

  // routed experts (after shared gemm2's plain store; atomics accumulate on top)
  exp_gemm1_kernel<<<dim3(IEXP / 64, N_TOK / 128, NEXP), 256, 0, stream>>>(
      xbf, WGU, ids, cnt, off, hexp);
  exp_gemm2_kernel<<<dim3(HDIM / 64, N_TOK / 128, NEXP), 256, 0, stream>>>(
      hexp, WDN, ids, tw, cnt, off, Out);
}

// Round 3
// 528.021 us; speedup vs baseline: 1.3759x; 1.0251x over previous
//
#include <hip/hip_runtime.h>
#include <hip/hip_bf16.h>
#include <stdint.h>

// MoE: N=8192 tokens, H=1024, E=16 experts (top-2), I=512, shared IS=2048.
// R3: expert weights pre-converted to bf16 (region reuse: WGU->sh region after
//     sg2, WDN->xbf region after eg1); eg1 B async staging; eg2 128x128 tile.

#define N_TOK 8192
#define HDIM 1024
#define NEXP 16
#define IEXP 512
#define ISH 2048

typedef __bf16 bf16x8 __attribute__((ext_vector_type(8)));
typedef float f32x4 __attribute__((ext_vector_type(4)));

// ---- ws layout (bytes) ----
#define OFF_XBF   ((size_t)0)            // 8192*1024*2 = 16,777,216  (dead after eg1 -> holds wdn_bf)
#define OFF_WSG   ((size_t)16777216)     // 2048*1024*2
#define OFF_WSU   ((size_t)20971520)
#define OFF_WSD   ((size_t)25165824)
#define OFF_SH    ((size_t)29360128)     // 8192*2048*2 = 33,554,432  (dead after sg2 -> holds wgu_bf 16*1024*1024*2)
#define OFF_HEXP  ((size_t)62914560)     // 16384*512*2
#define OFF_IDS   ((size_t)79691776)     // 16*8192*4
#define OFF_TW    ((size_t)80216064)     // 16*8192*4
#define OFF_META  ((size_t)80740352)     // cnt[16]@0, off[17]@64, probs_sum[16]@144
#define OFF_SIG   ((size_t)80740608)     // 8192*4
#define OFF_LG    ((size_t)80773376)     // 8192*32*4

static __device__ __forceinline__ unsigned short f2bf(float f) {
  unsigned int u = __float_as_uint(f);
  u += 0x7fffu + ((u >> 16) & 1u);
  return (unsigned short)(u >> 16);
}
static __device__ __forceinline__ int pack_bf2(float a, float b) {
  return (int)f2bf(a) | ((int)f2bf(b) << 16);
}
// async 16B global->LDS (LDS side must be lane-contiguous t*16; global side may gather)
static __device__ __forceinline__ void gl_lds16(const void* g, void* l) {
  __builtin_amdgcn_global_load_lds(
      (const __attribute__((address_space(1))) unsigned int*)g,
      (__attribute__((address_space(3))) unsigned int*)l, 16, 0, 0);
}

__global__ void cvt_kernel(const float* __restrict__ src,
                           unsigned short* __restrict__ dst, int n4) {
  int i = blockIdx.x * 256 + threadIdx.x;
  if (i >= n4) return;
  float4 v = ((const float4*)src)[i];
  uint2 o;
  o.x = (unsigned)pack_bf2(v.x, v.y);
  o.y = (unsigned)pack_bf2(v.z, v.w);
  ((uint2*)dst)[i] = o;
}

// ---- phase 1: logits (wave/token, butterfly reduce)
__global__ __launch_bounds__(256) void logits_kernel(
    const float* __restrict__ X, const float* __restrict__ GW,
    const float* __restrict__ SEGW, float* __restrict__ LG) {
  int wid = threadIdx.x >> 6, lane = threadIdx.x & 63;
  int tok = blockIdx.x * 4 + wid;
  const float* xr = X + (size_t)tok * HDIM;
  float xv[16];
#pragma unroll
  for (int i = 0; i < 16; i++) xv[i] = xr[lane + 64 * i];
  float myv = 0.f;
#pragma unroll
  for (int e = 0; e < 17; e++) {
    const float* wr = (e < 16) ? (GW + (size_t)e * HDIM) : SEGW;
    float p = 0.f;
#pragma unroll
    for (int i = 0; i < 16; i++) p += xv[i] * wr[lane + 64 * i];
#pragma unroll
    for (int off = 32; off >= 1; off >>= 1) p += __shfl_xor(p, off, 64);
    if (lane == e) myv = p;
  }
  if (lane < 17) LG[(size_t)tok * 32 + lane] = myv;
}

// ---- phase 2: softmax/top2/scatter, block-aggregated atomics
__global__ __launch_bounds__(256) void route_kernel(
    const float* __restrict__ LG, int* __restrict__ cnt,
    float* __restrict__ pps, int* __restrict__ ids,
    float* __restrict__ tw, float* __restrict__ sig) {
  __shared__ int lcnt[16];
  __shared__ int lbase[16];
  __shared__ float lps[16];
  int tid = threadIdx.x;
  int tok = blockIdx.x * 256 + tid;
  if (tid < 16) { lcnt[tid] = 0; lps[tid] = 0.f; }
  __syncthreads();
  const float4* row = (const float4*)(LG + (size_t)tok * 32);
  float4 v0 = row[0], v1 = row[1], v2 = row[2], v3 = row[3];
  float g16 = row[4].x;
  float lg[16] = {v0.x, v0.y, v0.z, v0.w, v1.x, v1.y, v1.z, v1.w,
                  v2.x, v2.y, v2.z, v2.w, v3.x, v3.y, v3.z, v3.w};
  float mx = lg[0];
#pragma unroll
  for (int e = 1; e < 16; e++) mx = fmaxf(mx, lg[e]);
  float pr[16], s = 0.f;
#pragma unroll
  for (int e = 0; e < 16; e++) { pr[e] = __expf(lg[e] - mx); s += pr[e]; }
  float inv_s = 1.f / s;
  float p1 = -1.f, p2 = -1.f; int i1 = 0, i2 = 0;
#pragma unroll
  for (int e = 0; e < 16; e++) {
    if (pr[e] > p1) { p2 = p1; i2 = i1; p1 = pr[e]; i1 = e; }
    else if (pr[e] > p2) { p2 = pr[e]; i2 = e; }
  }
  float wsum = p1 + p2;
  int s1 = atomicAdd(&lcnt[i1], 1);
  int s2 = atomicAdd(&lcnt[i2], 1);
#pragma unroll
  for (int e = 0; e < 16; e++) atomicAdd(&lps[e], pr[e] * inv_s);
  sig[tok] = 1.f / (1.f + __expf(-g16));
  __syncthreads();
  if (tid < 16) {
    lbase[tid] = atomicAdd(&cnt[tid], lcnt[tid]);
    atomicAdd(&pps[tid], lps[tid]);
  }
  __syncthreads();
  int d1 = i1 * N_TOK + lbase[i1] + s1;
  int d2 = i2 * N_TOK + lbase[i2] + s2;
  ids[d1] = tok; tw[d1] = p1 / wsum;
  ids[d2] = tok; tw[d2] = p2 / wsum;
}

__global__ void offs_aux_kernel(const int* __restrict__ cnt, int* __restrict__ off,
                                const float* __restrict__ probs_sum,
                                float* __restrict__ out_aux) {
  if (threadIdx.x == 0 && blockIdx.x == 0) {
    int run = 0; float aux = 0.f;
    for (int e = 0; e < NEXP; e++) {
      off[e] = run; run += cnt[e];
      aux += ((float)cnt[e] / (float)(N_TOK * 2)) * (probs_sum[e] / (float)N_TOK);
    }
    off[16] = run;
    *out_aux = (float)NEXP * aux;
  }
}

// ---- shared gemm1: H = silu(X@Wg^T) * (X@Wu^T), 128x(64g+64u) tile
__global__ __launch_bounds__(256) void shared_gemm1_kernel(
    const unsigned short* __restrict__ X, const unsigned short* __restrict__ Wg,
    const unsigned short* __restrict__ Wu, unsigned short* __restrict__ H) {
  __shared__ __align__(16) unsigned short As[128 * 32];
  __shared__ __align__(16) unsigned short Bs1[64 * 32];
  __shared__ __align__(16) unsigned short Bs2[64 * 32];
  int m0 = blockIdx.y * 128, n0 = blockIdx.x * 64;
  int t = threadIdx.x, lane = t & 63, w = t >> 6;
  int wm = (w & 1) * 64, wn = (w >> 1) * 32;
  int arow = t >> 2, akb = (t & 3) * 8;
  const unsigned short* ap0 = X + (size_t)(m0 + arow) * HDIM + akb;
  const unsigned short* ap1 = X + (size_t)(m0 + 64 + arow) * HDIM + akb;
  const unsigned short* bp1 = Wg + (size_t)(n0 + arow) * HDIM + akb;
  const unsigned short* bp2 = Wu + (size_t)(n0 + arow) * HDIM + akb;
  f32x4 z = {0.f, 0.f, 0.f, 0.f};
  f32x4 accg[4][2], accu[4][2];
#pragma unroll
  for (int i = 0; i < 4; i++)
#pragma unroll
    for (int j = 0; j < 2; j++) { accg[i][j] = z; accu[i][j] = z; }
  for (int k0 = 0; k0 < HDIM; k0 += 32) {
    __syncthreads();
    gl_lds16(ap0 + k0, &As[t * 8]);
    gl_lds16(ap1 + k0, &As[2048 + t * 8]);
    gl_lds16(bp1 + k0, &Bs1[t * 8]);
    gl_lds16(bp2 + k0, &Bs2[t * 8]);
    __syncthreads();
    int fr = lane & 15, fc = (lane >> 4) * 8;
    bf16x8 af[4], bg[2], bu[2];
#pragma unroll
    for (int i = 0; i < 4; i++) af[i] = *(const bf16x8*)&As[(wm + i * 16 + fr) * 32 + fc];
#pragma unroll
    for (int j = 0; j < 2; j++) {
      bg[j] = *(const bf16x8*)&Bs1[(wn + j * 16 + fr) * 32 + fc];
      bu[j] = *(const bf16x8*)&Bs2[(wn + j * 16 + fr) * 32 + fc];
    }
#pragma unroll
    for (int i = 0; i < 4; i++)
#pragma unroll
      for (int j = 0; j < 2; j++) {
        accg[i][j] = __builtin_amdgcn_mfma_f32_16x16x32_bf16(af[i], bg[j], accg[i][j], 0, 0, 0);
        accu[i][j] = __builtin_amdgcn_mfma_f32_16x16x32_bf16(af[i], bu[j], accu[i][j], 0, 0, 0);
      }
  }
  int col = lane & 15, rq = (lane >> 4) * 4;
#pragma unroll
  for (int i = 0; i < 4; i++)
#pragma unroll
    for (int j = 0; j < 2; j++)
#pragma unroll
      for (int r = 0; r < 4; r++) {
        int mm = m0 + wm + i * 16 + rq + r;
        int nn = n0 + wn + j * 16 + col;
        float g = accg[i][j][r], u = accu[i][j][r];
        float h = g / (1.f + __expf(-g)) * u;
        H[(size_t)mm * ISH + nn] = f2bf(h);
      }
}

// ---- shared gemm2: Out = (H@Wd^T) * sig[token]; 128x128 tile
__global__ __launch_bounds__(256) void shared_gemm2_kernel(
    const unsigned short* __restrict__ H, const unsigned short* __restrict__ Wd,
    const float* __restrict__ sig, float* __restrict__ Out) {
  __shared__ __align__(16) unsigned short As[128 * 32];
  __shared__ __align__(16) unsigned short Bs[128 * 32];
  int m0 = blockIdx.y * 128, n0 = blockIdx.x * 128;
  int t = threadIdx.x, lane = t & 63, w = t >> 6;
  int wm = (w & 1) * 64, wn = (w >> 1) * 64;
  int arow = t >> 2, akb = (t & 3) * 8;
  const unsigned short* apA0 = H + (size_t)(m0 + arow) * ISH + akb;
  const unsigned short* apA1 = H + (size_t)(m0 + 64 + arow) * ISH + akb;
  const unsigned short* apB0 = Wd + (size_t)(n0 + arow) * ISH + akb;
  const unsigned short* apB1 = Wd + (size_t)(n0 + 64 + arow) * ISH + akb;
  f32x4 z = {0.f, 0.f, 0.f, 0.f};
  f32x4 acc[4][4];
#pragma unroll
  for (int i = 0; i < 4; i++)
#pragma unroll
    for (int j = 0; j < 4; j++) acc[i][j] = z;
  for (int k0 = 0; k0 < ISH; k0 += 32) {
    __syncthreads();
    gl_lds16(apA0 + k0, &As[t * 8]);
    gl_lds16(apA1 + k0, &As[2048 + t * 8]);
    gl_lds16(apB0 + k0, &Bs[t * 8]);
    gl_lds16(apB1 + k0, &Bs[2048 + t * 8]);
    __syncthreads();
    int fr = lane & 15, fc = (lane >> 4) * 8;
    bf16x8 af[4], bfr[4];
#pragma unroll
    for (int i = 0; i < 4; i++) {
      af[i] = *(const bf16x8*)&As[(wm + i * 16 + fr) * 32 + fc];
      bfr[i] = *(const bf16x8*)&Bs[(wn + i * 16 + fr) * 32 + fc];
    }
#pragma unroll
    for (int i = 0; i < 4; i++)
#pragma unroll
      for (int j = 0; j < 4; j++)
        acc[i][j] = __builtin_amdgcn_mfma_f32_16x16x32_bf16(af[i], bfr[j], acc[i][j], 0, 0, 0);
  }
  int col = lane & 15, rq = (lane >> 4) * 4;
#pragma unroll
  for (int i = 0; i < 4; i++)
#pragma unroll
    for (int r = 0; r < 4; r++) {
      int mm = m0 + wm + i * 16 + rq + r;
      float sg = sig[mm];
#pragma unroll
      for (int j = 0; j < 4; j++) {
        int nn = n0 + wn + j * 16 + col;
        Out[(size_t)mm * HDIM + nn] = acc[i][j][r] * sg;
      }
    }
}

// ---- expert gemm1 (grouped, gathered A, bf16 weights): Hexp = silu(g)*u
__global__ __launch_bounds__(256) void exp_gemm1_kernel(
    const unsigned short* __restrict__ X, const unsigned short* __restrict__ WGUb,
    const int* __restrict__ ids, const int* __restrict__ cnt,
    const int* __restrict__ off, unsigned short* __restrict__ Hexp) {
  int e = blockIdx.z;
  int ne = cnt[e];
  int m0 = blockIdx.y * 128;
  if (m0 >= ne) return;
  __shared__ __align__(16) unsigned short As[128 * 32];
  __shared__ __align__(16) unsigned short Bs1[64 * 32];
  __shared__ __align__(16) unsigned short Bs2[64 * 32];
  int n0 = blockIdx.x * 64;
  const int* eids = ids + e * N_TOK;
  int base = off[e];
  int t = threadIdx.x, lane = t & 63, w = t >> 6;
  int wm = (w & 1) * 64, wn = (w >> 1) * 32;
  int arow = t >> 2, akb = (t & 3) * 8;
  int s0 = m0 + arow, s1 = m0 + 64 + arow;
  int t0 = (s0 < ne) ? eids[s0] : 0;
  int t1 = (s1 < ne) ? eids[s1] : 0;
  const unsigned short* ap0 = X + (size_t)t0 * HDIM + akb;
  const unsigned short* ap1 = X + (size_t)t1 * HDIM + akb;
  const unsigned short* bpg = WGUb + ((size_t)e * 1024 + n0 + arow) * HDIM + akb;
  const unsigned short* bpu = WGUb + ((size_t)e * 1024 + 512 + n0 + arow) * HDIM + akb;
  f32x4 z = {0.f, 0.f, 0.f, 0.f};
  f32x4 accg[4][2], accu[4][2];
#pragma unroll
  for (int i = 0; i < 4; i++)
#pragma unroll
    for (int j = 0; j < 2; j++) { accg[i][j] = z; accu[i][j] = z; }
  for (int k0 = 0; k0 < HDIM; k0 += 32) {
    __syncthreads();
    gl_lds16(ap0 + k0, &As[t * 8]);
    gl_lds16(ap1 + k0, &As[2048 + t * 8]);
    gl_lds16(bpg + k0, &Bs1[t * 8]);
    gl_lds16(bpu + k0, &Bs2[t * 8]);
    __syncthreads();
    int fr = lane & 15, fc = (lane >> 4) * 8;
    bf16x8 af[4], bg[2], bu[2];
#pragma unroll
    for (int i = 0; i < 4; i++) af[i] = *(const bf16x8*)&As[(wm + i * 16 + fr) * 32 + fc];
#pragma unroll
    for (int j = 0; j < 2; j++) {
      bg[j] = *(const bf16x8*)&Bs1[(wn + j * 16 + fr) * 32 + fc];
      bu[j] = *(const bf16x8*)&Bs2[(wn + j * 16 + fr) * 32 + fc];
    }
#pragma unroll
    for (int i = 0; i < 4; i++)
#pragma unroll
      for (int j = 0; j < 2; j++) {
        accg[i][j] = __builtin_amdgcn_mfma_f32_16x16x32_bf16(af[i], bg[j], accg[i][j], 0, 0, 0);
        accu[i][j] = __builtin_amdgcn_mfma_f32_16x16x32_bf16(af[i], bu[j], accu[i][j], 0, 0, 0);
      }
  }
  int col = lane & 15, rq = (lane >> 4) * 4;
#pragma unroll
  for (int i = 0; i < 4; i++)
#pragma unroll
    for (int j = 0; j < 2; j++)
#pragma unroll
      for (int r = 0; r < 4; r++) {
        int slot = m0 + wm + i * 16 + rq + r;
        if (slot < ne) {
          int nn = n0 + wn + j * 16 + col;
          float g = accg[i][j][r], u = accu[i][j][r];
          float h = g / (1.f + __expf(-g)) * u;
          Hexp[(size_t)(base + slot) * IEXP + nn] = f2bf(h);
        }
      }
}

// ---- expert gemm2 (grouped, bf16 weights, 128x128): atomicAdd(Out, tw * (Hexp@Wd^T))
__global__ __launch_bounds__(256) void exp_gemm2_kernel(
    const unsigned short* __restrict__ Hexp, const unsigned short* __restrict__ WDb,
    const int* __restrict__ ids, const float* __restrict__ tw,
    const int* __restrict__ cnt, const int* __restrict__ off,
    float* __restrict__ Out) {
  int e = blockIdx.z;
  int ne = cnt[e];
  int m0 = blockIdx.y * 128;
  if (m0 >= ne) return;
  __shared__ __align__(16) unsigned short As[128 * 32];
  __shared__ __align__(16) unsigned short Bs[128 * 32];
  int n0 = blockIdx.x * 128;
  const int* eids = ids + e * N_TOK;
  const float* etw = tw + e * N_TOK;
  int base = off[e];
  int t = threadIdx.x, lane = t & 63, w = t >> 6;
  int wm = (w & 1) * 64, wn = (w >> 1) * 64;
  int arow = t >> 2, akb = (t & 3) * 8;
  int ra0 = base + m0 + arow;        if (ra0 > 16383) ra0 = 16383;
  int ra1 = base + m0 + 64 + arow;   if (ra1 > 16383) ra1 = 16383;
  const unsigned short* ap0 = Hexp + (size_t)ra0 * IEXP + akb;
  const unsigned short* ap1 = Hexp + (size_t)ra1 * IEXP + akb;
  const unsigned short* bp0 = WDb + ((size_t)e * HDIM + n0 + arow) * IEXP + akb;
  const unsigned short* bp1 = WDb + ((size_t)e * HDIM + n0 + 64 + arow) * IEXP + akb;
  f32x4 z = {0.f, 0.f, 0.f, 0.f};
  f32x4 acc[4][4];
#pragma unroll
  for (int i = 0; i < 4; i++)
#pragma unroll
    for (int j = 0; j < 4; j++) acc[i][j] = z;
  for (int k0 = 0; k0 < IEXP; k0 += 32) {
    __syncthreads();
    gl_lds16(ap0 + k0, &As[t * 8]);
    gl_lds16(ap1 + k0, &As[2048 + t * 8]);
    gl_lds16(bp0 + k0, &Bs[t * 8]);
    gl_lds16(bp1 + k0, &Bs[2048 + t * 8]);
    __syncthreads();
    int fr = lane & 15, fc = (lane >> 4) * 8;
    bf16x8 af[4], bfr[4];
#pragma unroll
    for (int i = 0; i < 4; i++) {
      af[i] = *(const bf16x8*)&As[(wm + i * 16 + fr) * 32 + fc];
      bfr[i] = *(const bf16x8*)&Bs[(wn + i * 16 + fr) * 32 + fc];
    }
#pragma unroll
    for (int i = 0; i < 4; i++)
#pragma unroll
      for (int j = 0; j < 4; j++)
        acc[i][j] = __builtin_amdgcn_mfma_f32_16x16x32_bf16(af[i], bfr[j], acc[i][j], 0, 0, 0);
  }
  int col = lane & 15, rq = (lane >> 4) * 4;
#pragma unroll
  for (int i = 0; i < 4; i++)
#pragma unroll
    for (int r = 0; r < 4; r++) {
      int slot = m0 + wm + i * 16 + rq + r;
      if (slot < ne) {
        int tok = eids[slot];
        float wgt = etw[slot];
#pragma unroll
        for (int j = 0; j < 4; j++) {
          int nn = n0 + wn + j * 16 + col;
          atomicAdd(&Out[(size_t)tok * HDIM + nn], acc[i][j][r] * wgt);
        }
      }
    }
}

extern "C" void kernel_launch(void* const* d_in, const int* in_sizes, int n_in,
                              void* d_out, int out_size, void* d_ws, size_t ws_size,
                              hipStream_t stream) {
  const float* X   = (const float*)d_in[0];
  const float* GW  = (const float*)d_in[1];
  const float* WGU = (const float*)d_in[2];
  const float* WDN = (const float*)d_in[3];
  const float* WSG = (const float*)d_in[4];
  const float* WSU = (const float*)d_in[5];
  const float* WSD = (const float*)d_in[6];
  const float* SEGW = (const float*)d_in[7];
  float* Out = (float*)d_out;
  char* ws = (char*)d_ws;

  unsigned short* xbf  = (unsigned short*)(ws + OFF_XBF);
  unsigned short* wsg  = (unsigned short*)(ws + OFF_WSG);
  unsigned short* wsu  = (unsigned short*)(ws + OFF_WSU);
  unsigned short* wsd  = (unsigned short*)(ws + OFF_WSD);
  unsigned short* sh   = (unsigned short*)(ws + OFF_SH);
  unsigned short* hexp = (unsigned short*)(ws + OFF_HEXP);
  int*   ids  = (int*)(ws + OFF_IDS);
  float* tw   = (float*)(ws + OFF_TW);
  int*   cnt  = (int*)(ws + OFF_META);
  int*   off  = (int*)(ws + OFF_META + 64);
  float* pps  = (float*)(ws + OFF_META + 144);
  float* sig  = (float*)(ws + OFF_SIG);
  float* lg   = (float*)(ws + OFF_LG);
  // region reuse (stream-ordered): wgu_bf over sh (dead after sg2),
  // wdn_bf over xbf (dead after eg1)
  unsigned short* wgu_bf = (unsigned short*)(ws + OFF_SH);
  unsigned short* wdn_bf = (unsigned short*)(ws + OFF_XBF);

  hipMemsetAsync(ws + OFF_META, 0, 256, stream);

  // f32 -> bf16 converts (activation + shared weights)
  {
    int n4;
    n4 = (N_TOK * HDIM) / 4;
    cvt_kernel<<<(n4 + 255) / 256, 256, 0, stream>>>(X, xbf, n4);
    n4 = (ISH * HDIM) / 4;
    cvt_kernel<<<(n4 + 255) / 256, 256, 0, stream>>>(WSG, wsg, n4);
    cvt_kernel<<<(n4 + 255) / 256, 256, 0, stream>>>(WSU, wsu, n4);
    n4 = (HDIM * ISH) / 4;
    cvt_kernel<<<(n4 + 255) / 256, 256, 0, stream>>>(WSD, wsd, n4);
  }

  logits_kernel<<<N_TOK / 4, 256, 0, stream>>>(X, GW, SEGW, lg);
  route_kernel<<<N_TOK / 256, 256, 0, stream>>>(lg, cnt, pps, ids, tw, sig);
  offs_aux_kernel<<<1, 64, 0, stream>>>(cnt, off, pps, Out + (size_t)N_TOK * HDIM);

  // shared expert
  shared_gemm1_kernel<<<dim3(ISH / 64, N_TOK / 128), 256, 0, stream>>>(xbf, wsg, wsu, sh);
  shared_gemm2_kernel<<<dim3(HDIM / 128, N_TOK / 128), 256, 0, stream>>>(sh, wsd, sig, Out);

  // expert weight converts into dead regions
  {
    int n4 = (NEXP * 2 * IEXP * HDIM) / 4;  // 4,194,304
    cvt_kernel<<<(n4 + 255) / 256, 256, 0, stream>>>(WGU, wgu_bf, n4);
  }
  exp_gemm1_kernel<<<dim3(IEXP / 64, N_TOK / 128, NEXP), 256, 0, stream>>>(
      xbf, wgu_bf, ids, cnt, off, hexp);
  {
    int n4 = (NEXP * HDIM * IEXP) / 4;      // 2,097,152
    cvt_kernel<<<(n4 + 255) / 256, 256, 0, stream>>>(WDN, wdn_bf, n4);
  }
  exp_gemm2_kernel<<<dim3(HDIM / 128, N_TOK / 128, NEXP), 256, 0, stream>>>(
      hexp, wdn_bf, ids, tw, cnt, off, Out);
}

// Round 4
// 491.478 us; speedup vs baseline: 1.4782x; 1.0744x over previous
//
#include <hip/hip_runtime.h>
#include <hip/hip_bf16.h>
#include <stdint.h>

// MoE: N=8192 tokens, H=1024, E=16 experts (top-2), I=512, shared IS=2048.
// R4: no output atomics (eg2 plain-stores to eout; combine kernel gathers
//     per-token expert rows), X cvt fused into logits kernel.

#define N_TOK 8192
#define HDIM 1024
#define NEXP 16
#define IEXP 512
#define ISH 2048

typedef __bf16 bf16x8 __attribute__((ext_vector_type(8)));
typedef float f32x4 __attribute__((ext_vector_type(4)));

// ---- ws layout (bytes) ----
#define OFF_XBF   ((size_t)0)            // 16,777,216 (dead after eg1 -> wdn_bf)
#define OFF_WSG   ((size_t)16777216)     // 4,194,304
#define OFF_WSU   ((size_t)20971520)
#define OFF_WSD   ((size_t)25165824)
#define OFF_SH    ((size_t)29360128)     // 33,554,432 (H matrix; dead after sg2 -> wgu_bf; dead after eg1 -> eout)
#define OFF_HEXP  ((size_t)62914560)     // 16,777,216
#define OFF_IDS   ((size_t)79691776)     // 16*8192*4 = 524,288
#define OFF_META  ((size_t)80216064)     // 256 B: cnt[16]@0, off[17]@64, probs_sum[16]@144
#define OFF_SIG   ((size_t)80216320)     // 8192*4
#define OFF_LG    ((size_t)80249088)     // 8192*32*4 = 1,048,576
#define OFF_SLOT  ((size_t)81297664)     // 2*8192*4
#define OFF_TWAB  ((size_t)81363200)     // 2*8192*4

static __device__ __forceinline__ unsigned short f2bf(float f) {
  unsigned int u = __float_as_uint(f);
  u += 0x7fffu + ((u >> 16) & 1u);
  return (unsigned short)(u >> 16);
}
static __device__ __forceinline__ int pack_bf2(float a, float b) {
  return (int)f2bf(a) | ((int)f2bf(b) << 16);
}
static __device__ __forceinline__ float bf2f(unsigned short u) {
  return __uint_as_float(((unsigned int)u) << 16);
}
// async 16B global->LDS (LDS dest is wave-uniform base + lane*16)
static __device__ __forceinline__ void gl_lds16(const void* g, void* l) {
  __builtin_amdgcn_global_load_lds(
      (const __attribute__((address_space(1))) unsigned int*)g,
      (__attribute__((address_space(3))) unsigned int*)l, 16, 0, 0);
}

__global__ void cvt_kernel(const float* __restrict__ src,
                           unsigned short* __restrict__ dst, int n4) {
  int i = blockIdx.x * 256 + threadIdx.x;
  if (i >= n4) return;
  float4 v = ((const float4*)src)[i];
  uint2 o;
  o.x = (unsigned)pack_bf2(v.x, v.y);
  o.y = (unsigned)pack_bf2(v.z, v.w);
  ((uint2*)dst)[i] = o;
}

// ---- phase 1: logits (wave/token) + fused X->bf16 convert
__global__ __launch_bounds__(256) void logits_kernel(
    const float* __restrict__ X, const float* __restrict__ GW,
    const float* __restrict__ SEGW, float* __restrict__ LG,
    unsigned short* __restrict__ XBF) {
  int wid = threadIdx.x >> 6, lane = threadIdx.x & 63;
  int tok = blockIdx.x * 4 + wid;
  const float* xr = X + (size_t)tok * HDIM;
  unsigned short* xw = XBF + (size_t)tok * HDIM;
  float xv[16];
#pragma unroll
  for (int i = 0; i < 16; i++) xv[i] = xr[lane + 64 * i];
#pragma unroll
  for (int i = 0; i < 16; i++) xw[lane + 64 * i] = f2bf(xv[i]);
  float myv = 0.f;
#pragma unroll
  for (int e = 0; e < 17; e++) {
    const float* wr = (e < 16) ? (GW + (size_t)e * HDIM) : SEGW;
    float p = 0.f;
#pragma unroll
    for (int i = 0; i < 16; i++) p += xv[i] * wr[lane + 64 * i];
#pragma unroll
    for (int off = 32; off >= 1; off >>= 1) p += __shfl_xor(p, off, 64);
    if (lane == e) myv = p;
  }
  if (lane < 17) LG[(size_t)tok * 32 + lane] = myv;
}

// ---- phase 2: softmax/top2/scatter, block-aggregated atomics; records
// per-token (expert,slot) + weights for the combine kernel
__global__ __launch_bounds__(256) void route_kernel(
    const float* __restrict__ LG, int* __restrict__ cnt,
    float* __restrict__ pps, int* __restrict__ ids,
    int* __restrict__ slotAB, float* __restrict__ twAB,
    float* __restrict__ sig) {
  __shared__ int lcnt[16];
  __shared__ int lbase[16];
  __shared__ float lps[16];
  int tid = threadIdx.x;
  int tok = blockIdx.x * 256 + tid;
  if (tid < 16) { lcnt[tid] = 0; lps[tid] = 0.f; }
  __syncthreads();
  const float4* row = (const float4*)(LG + (size_t)tok * 32);
  float4 v0 = row[0], v1 = row[1], v2 = row[2], v3 = row[3];
  float g16 = row[4].x;
  float lg[16] = {v0.x, v0.y, v0.z, v0.w, v1.x, v1.y, v1.z, v1.w,
                  v2.x, v2.y, v2.z, v2.w, v3.x, v3.y, v3.z, v3.w};
  float mx = lg[0];
#pragma unroll
  for (int e = 1; e < 16; e++) mx = fmaxf(mx, lg[e]);
  float pr[16], s = 0.f;
#pragma unroll
  for (int e = 0; e < 16; e++) { pr[e] = __expf(lg[e] - mx); s += pr[e]; }
  float inv_s = 1.f / s;
  float p1 = -1.f, p2 = -1.f; int i1 = 0, i2 = 0;
#pragma unroll
  for (int e = 0; e < 16; e++) {
    if (pr[e] > p1) { p2 = p1; i2 = i1; p1 = pr[e]; i1 = e; }
    else if (pr[e] > p2) { p2 = pr[e]; i2 = e; }
  }
  float wsum = p1 + p2;
  int s1 = atomicAdd(&lcnt[i1], 1);
  int s2 = atomicAdd(&lcnt[i2], 1);
#pragma unroll
  for (int e = 0; e < 16; e++) atomicAdd(&lps[e], pr[e] * inv_s);
  sig[tok] = 1.f / (1.f + __expf(-g16));
  __syncthreads();
  if (tid < 16) {
    lbase[tid] = atomicAdd(&cnt[tid], lcnt[tid]);
    atomicAdd(&pps[tid], lps[tid]);
  }
  __syncthreads();
  int sl1 = lbase[i1] + s1, sl2 = lbase[i2] + s2;
  ids[i1 * N_TOK + sl1] = tok;
  ids[i2 * N_TOK + sl2] = tok;
  slotAB[tok * 2]     = (i1 << 14) | sl1;
  slotAB[tok * 2 + 1] = (i2 << 14) | sl2;
  twAB[tok * 2]     = p1 / wsum;
  twAB[tok * 2 + 1] = p2 / wsum;
}

__global__ void offs_aux_kernel(const int* __restrict__ cnt, int* __restrict__ off,
                                const float* __restrict__ probs_sum,
                                float* __restrict__ out_aux) {
  if (threadIdx.x == 0 && blockIdx.x == 0) {
    int run = 0; float aux = 0.f;
    for (int e = 0; e < NEXP; e++) {
      off[e] = run; run += cnt[e];
      aux += ((float)cnt[e] / (float)(N_TOK * 2)) * (probs_sum[e] / (float)N_TOK);
    }
    off[16] = run;
    *out_aux = (float)NEXP * aux;
  }
}

// ---- shared gemm1: H = silu(X@Wg^T) * (X@Wu^T)
__global__ __launch_bounds__(256) void shared_gemm1_kernel(
    const unsigned short* __restrict__ X, const unsigned short* __restrict__ Wg,
    const unsigned short* __restrict__ Wu, unsigned short* __restrict__ H) {
  __shared__ __align__(16) unsigned short As[128 * 32];
  __shared__ __align__(16) unsigned short Bs1[64 * 32];
  __shared__ __align__(16) unsigned short Bs2[64 * 32];
  int m0 = blockIdx.y * 128, n0 = blockIdx.x * 64;
  int t = threadIdx.x, lane = t & 63, w = t >> 6;
  int wm = (w & 1) * 64, wn = (w >> 1) * 32;
  int arow = t >> 2, akb = (t & 3) * 8;
  const unsigned short* ap0 = X + (size_t)(m0 + arow) * HDIM + akb;
  const unsigned short* ap1 = X + (size_t)(m0 + 64 + arow) * HDIM + akb;
  const unsigned short* bp1 = Wg + (size_t)(n0 + arow) * HDIM + akb;
  const unsigned short* bp2 = Wu + (size_t)(n0 + arow) * HDIM + akb;
  f32x4 z = {0.f, 0.f, 0.f, 0.f};
  f32x4 accg[4][2], accu[4][2];
#pragma unroll
  for (int i = 0; i < 4; i++)
#pragma unroll
    for (int j = 0; j < 2; j++) { accg[i][j] = z; accu[i][j] = z; }
  for (int k0 = 0; k0 < HDIM; k0 += 32) {
    __syncthreads();
    gl_lds16(ap0 + k0, &As[t * 8]);
    gl_lds16(ap1 + k0, &As[2048 + t * 8]);
    gl_lds16(bp1 + k0, &Bs1[t * 8]);
    gl_lds16(bp2 + k0, &Bs2[t * 8]);
    __syncthreads();
    int fr = lane & 15, fc = (lane >> 4) * 8;
    bf16x8 af[4], bg[2], bu[2];
#pragma unroll
    for (int i = 0; i < 4; i++) af[i] = *(const bf16x8*)&As[(wm + i * 16 + fr) * 32 + fc];
#pragma unroll
    for (int j = 0; j < 2; j++) {
      bg[j] = *(const bf16x8*)&Bs1[(wn + j * 16 + fr) * 32 + fc];
      bu[j] = *(const bf16x8*)&Bs2[(wn + j * 16 + fr) * 32 + fc];
    }
#pragma unroll
    for (int i = 0; i < 4; i++)
#pragma unroll
      for (int j = 0; j < 2; j++) {
        accg[i][j] = __builtin_amdgcn_mfma_f32_16x16x32_bf16(af[i], bg[j], accg[i][j], 0, 0, 0);
        accu[i][j] = __builtin_amdgcn_mfma_f32_16x16x32_bf16(af[i], bu[j], accu[i][j], 0, 0, 0);
      }
  }
  int col = lane & 15, rq = (lane >> 4) * 4;
#pragma unroll
  for (int i = 0; i < 4; i++)
#pragma unroll
    for (int j = 0; j < 2; j++)
#pragma unroll
      for (int r = 0; r < 4; r++) {
        int mm = m0 + wm + i * 16 + rq + r;
        int nn = n0 + wn + j * 16 + col;
        float g = accg[i][j][r], u = accu[i][j][r];
        float h = g / (1.f + __expf(-g)) * u;
        H[(size_t)mm * ISH + nn] = f2bf(h);
      }
}

// ---- shared gemm2: Out = (H@Wd^T) * sig[token]; 128x128 tile, plain store
__global__ __launch_bounds__(256) void shared_gemm2_kernel(
    const unsigned short* __restrict__ H, const unsigned short* __restrict__ Wd,
    const float* __restrict__ sig, float* __restrict__ Out) {
  __shared__ __align__(16) unsigned short As[128 * 32];
  __shared__ __align__(16) unsigned short Bs[128 * 32];
  int m0 = blockIdx.y * 128, n0 = blockIdx.x * 128;
  int t = threadIdx.x, lane = t & 63, w = t >> 6;
  int wm = (w & 1) * 64, wn = (w >> 1) * 64;
  int arow = t >> 2, akb = (t & 3) * 8;
  const unsigned short* apA0 = H + (size_t)(m0 + arow) * ISH + akb;
  const unsigned short* apA1 = H + (size_t)(m0 + 64 + arow) * ISH + akb;
  const unsigned short* apB0 = Wd + (size_t)(n0 + arow) * ISH + akb;
  const unsigned short* apB1 = Wd + (size_t)(n0 + 64 + arow) * ISH + akb;
  f32x4 z = {0.f, 0.f, 0.f, 0.f};
  f32x4 acc[4][4];
#pragma unroll
  for (int i = 0; i < 4; i++)
#pragma unroll
    for (int j = 0; j < 4; j++) acc[i][j] = z;
  for (int k0 = 0; k0 < ISH; k0 += 32) {
    __syncthreads();
    gl_lds16(apA0 + k0, &As[t * 8]);
    gl_lds16(apA1 + k0, &As[2048 + t * 8]);
    gl_lds16(apB0 + k0, &Bs[t * 8]);
    gl_lds16(apB1 + k0, &Bs[2048 + t * 8]);
    __syncthreads();
    int fr = lane & 15, fc = (lane >> 4) * 8;
    bf16x8 af[4], bfr[4];
#pragma unroll
    for (int i = 0; i < 4; i++) {
      af[i] = *(const bf16x8*)&As[(wm + i * 16 + fr) * 32 + fc];
      bfr[i] = *(const bf16x8*)&Bs[(wn + i * 16 + fr) * 32 + fc];
    }
#pragma unroll
    for (int i = 0; i < 4; i++)
#pragma unroll
      for (int j = 0; j < 4; j++)
        acc[i][j] = __builtin_amdgcn_mfma_f32_16x16x32_bf16(af[i], bfr[j], acc[i][j], 0, 0, 0);
  }
  int col = lane & 15, rq = (lane >> 4) * 4;
#pragma unroll
  for (int i = 0; i < 4; i++)
#pragma unroll
    for (int r = 0; r < 4; r++) {
      int mm = m0 + wm + i * 16 + rq + r;
      float sg = sig[mm];
#pragma unroll
      for (int j = 0; j < 4; j++) {
        int nn = n0 + wn + j * 16 + col;
        Out[(size_t)mm * HDIM + nn] = acc[i][j][r] * sg;
      }
    }
}

// ---- expert gemm1 (grouped, gathered A, bf16 weights): Hexp = silu(g)*u
__global__ __launch_bounds__(256) void exp_gemm1_kernel(
    const unsigned short* __restrict__ X, const unsigned short* __restrict__ WGUb,
    const int* __restrict__ ids, const int* __restrict__ cnt,
    const int* __restrict__ off, unsigned short* __restrict__ Hexp) {
  int e = blockIdx.z;
  int ne = cnt[e];
  int m0 = blockIdx.y * 128;
  if (m0 >= ne) return;
  __shared__ __align__(16) unsigned short As[128 * 32];
  __shared__ __align__(16) unsigned short Bs1[64 * 32];
  __shared__ __align__(16) unsigned short Bs2[64 * 32];
  int n0 = blockIdx.x * 64;
  const int* eids = ids + e * N_TOK;
  int base = off[e];
  int t = threadIdx.x, lane = t & 63, w = t >> 6;
  int wm = (w & 1) * 64, wn = (w >> 1) * 32;
  int arow = t >> 2, akb = (t & 3) * 8;
  int s0 = m0 + arow, s1 = m0 + 64 + arow;
  int t0 = (s0 < ne) ? eids[s0] : 0;
  int t1 = (s1 < ne) ? eids[s1] : 0;
  const unsigned short* ap0 = X + (size_t)t0 * HDIM + akb;
  const unsigned short* ap1 = X + (size_t)t1 * HDIM + akb;
  const unsigned short* bpg = WGUb + ((size_t)e * 1024 + n0 + arow) * HDIM + akb;
  const unsigned short* bpu = WGUb + ((size_t)e * 1024 + 512 + n0 + arow) * HDIM + akb;
  f32x4 z = {0.f, 0.f, 0.f, 0.f};
  f32x4 accg[4][2], accu[4][2];
#pragma unroll
  for (int i = 0; i < 4; i++)
#pragma unroll
    for (int j = 0; j < 2; j++) { accg[i][j] = z; accu[i][j] = z; }
  for (int k0 = 0; k0 < HDIM; k0 += 32) {
    __syncthreads();
    gl_lds16(ap0 + k0, &As[t * 8]);
    gl_lds16(ap1 + k0, &As[2048 + t * 8]);
    gl_lds16(bpg + k0, &Bs1[t * 8]);
    gl_lds16(bpu + k0, &Bs2[t * 8]);
    __syncthreads();
    int fr = lane & 15, fc = (lane >> 4) * 8;
    bf16x8 af[4], bg[2], bu[2];
#pragma unroll
    for (int i = 0; i < 4; i++) af[i] = *(const bf16x8*)&As[(wm + i * 16 + fr) * 32 + fc];
#pragma unroll
    for (int j = 0; j < 2; j++) {
      bg[j] = *(const bf16x8*)&Bs1[(wn + j * 16 + fr) * 32 + fc];
      bu[j] = *(const bf16x8*)&Bs2[(wn + j * 16 + fr) * 32 + fc];
    }
#pragma unroll
    for (int i = 0; i < 4; i++)
#pragma unroll
      for (int j = 0; j < 2; j++) {
        accg[i][j] = __builtin_amdgcn_mfma_f32_16x16x32_bf16(af[i], bg[j], accg[i][j], 0, 0, 0);
        accu[i][j] = __builtin_amdgcn_mfma_f32_16x16x32_bf16(af[i], bu[j], accu[i][j], 0, 0, 0);
      }
  }
  int col = lane & 15, rq = (lane >> 4) * 4;
#pragma unroll
  for (int i = 0; i < 4; i++)
#pragma unroll
    for (int j = 0; j < 2; j++)
#pragma unroll
      for (int r = 0; r < 4; r++) {
        int slot = m0 + wm + i * 16 + rq + r;
        if (slot < ne) {
          int nn = n0 + wn + j * 16 + col;
          float g = accg[i][j][r], u = accu[i][j][r];
          float h = g / (1.f + __expf(-g)) * u;
          Hexp[(size_t)(base + slot) * IEXP + nn] = f2bf(h);
        }
      }
}

// ---- expert gemm2 (grouped, bf16 weights, 128x128): eout = Hexp@Wd^T (raw, bf16)
__global__ __launch_bounds__(256) void exp_gemm2_kernel(
    const unsigned short* __restrict__ Hexp, const unsigned short* __restrict__ WDb,
    const int* __restrict__ cnt, const int* __restrict__ off,
    unsigned short* __restrict__ Eout) {
  int e = blockIdx.z;
  int ne = cnt[e];
  int m0 = blockIdx.y * 128;
  if (m0 >= ne) return;
  __shared__ __align__(16) unsigned short As[128 * 32];
  __shared__ __align__(16) unsigned short Bs[128 * 32];
  int n0 = blockIdx.x * 128;
  int base = off[e];
  int t = threadIdx.x, lane = t & 63, w = t >> 6;
  int wm = (w & 1) * 64, wn = (w >> 1) * 64;
  int arow = t >> 2, akb = (t & 3) * 8;
  int ra0 = base + m0 + arow;        if (ra0 > 16383) ra0 = 16383;
  int ra1 = base + m0 + 64 + arow;   if (ra1 > 16383) ra1 = 16383;
  const unsigned short* ap0 = Hexp + (size_t)ra0 * IEXP + akb;
  const unsigned short* ap1 = Hexp + (size_t)ra1 * IEXP + akb;
  const unsigned short* bp0 = WDb + ((size_t)e * HDIM + n0 + arow) * IEXP + akb;
  const unsigned short* bp1 = WDb + ((size_t)e * HDIM + n0 + 64 + arow) * IEXP + akb;
  f32x4 z = {0.f, 0.f, 0.f, 0.f};
  f32x4 acc[4][4];
#pragma unroll
  for (int i = 0; i < 4; i++)
#pragma unroll
    for (int j = 0; j < 4; j++) acc[i][j] = z;
  for (int k0 = 0; k0 < IEXP; k0 += 32) {
    __syncthreads();
    gl_lds16(ap0 + k0, &As[t * 8]);
    gl_lds16(ap1 + k0, &As[2048 + t * 8]);
    gl_lds16(bp0 + k0, &Bs[t * 8]);
    gl_lds16(bp1 + k0, &Bs[2048 + t * 8]);
    __syncthreads();
    int fr = lane & 15, fc = (lane >> 4) * 8;
    bf16x8 af[4], bfr[4];
#pragma unroll
    for (int i = 0; i < 4; i++) {
      af[i] = *(const bf16x8*)&As[(wm + i * 16 + fr) * 32 + fc];
      bfr[i] = *(const bf16x8*)&Bs[(wn + i * 16 + fr) * 32 + fc];
    }
#pragma unroll
    for (int i = 0; i < 4; i++)
#pragma unroll
      for (int j = 0; j < 4; j++)
        acc[i][j] = __builtin_amdgcn_mfma_f32_16x16x32_bf16(af[i], bfr[j], acc[i][j], 0, 0, 0);
  }
  int col = lane & 15, rq = (lane >> 4) * 4;
#pragma unroll
  for (int i = 0; i < 4; i++)
#pragma unroll
    for (int r = 0; r < 4; r++) {
      int slot = m0 + wm + i * 16 + rq + r;
      if (slot < ne) {
#pragma unroll
        for (int j = 0; j < 4; j++) {
          int nn = n0 + wn + j * 16 + col;
          Eout[(size_t)(base + slot) * HDIM + nn] = f2bf(acc[i][j][r]);
        }
      }
    }
}

// ---- combine: Out[tok] += twA*eout[rowA] + twB*eout[rowB]
__global__ __launch_bounds__(256) void combine_kernel(
    const unsigned short* __restrict__ Eout, const int* __restrict__ slotAB,
    const float* __restrict__ twAB, const int* __restrict__ off,
    float* __restrict__ Out) {
  int tok = blockIdx.x, t = threadIdx.x;
  int sa = slotAB[tok * 2], sb = slotAB[tok * 2 + 1];
  float wa = twAB[tok * 2], wb = twAB[tok * 2 + 1];
  int ra = off[sa >> 14] + (sa & 16383);
  int rb = off[sb >> 14] + (sb & 16383);
  const ushort4 a4 = *(const ushort4*)(Eout + (size_t)ra * HDIM + t * 4);
  const ushort4 b4 = *(const ushort4*)(Eout + (size_t)rb * HDIM + t * 4);
  float* po = Out + (size_t)tok * HDIM + t * 4;
  float4 o = *(const float4*)po;
  o.x += wa * bf2f(a4.x) + wb * bf2f(b4.x);
  o.y += wa * bf2f(a4.y) + wb * bf2f(b4.y);
  o.z += wa * bf2f(a4.z) + wb * bf2f(b4.z);
  o.w += wa * bf2f(a4.w) + wb * bf2f(b4.w);
  *(float4*)po = o;
}

extern "C" void kernel_launch(void* const* d_in, const int* in_sizes, int n_in,
                              void* d_out, int out_size, void* d_ws, size_t ws_size,
                              hipStream_t stream) {
  const float* X   = (const float*)d_in[0];
  const float* GW  = (const float*)d_in[1];
  const float* WGU = (const float*)d_in[2];
  const float* WDN = (const float*)d_in[3];
  const float* WSG = (const float*)d_in[4];
  const float* WSU = (const float*)d_in[5];
  const float* WSD = (const float*)d_in[6];
  const float* SEGW = (const float*)d_in[7];
  float* Out = (float*)d_out;
  char* ws = (char*)d_ws;

  unsigned short* xbf  = (unsigned short*)(ws + OFF_XBF);
  unsigned short* wsg  = (unsigned short*)(ws + OFF_WSG);
  unsigned short* wsu  = (unsigned short*)(ws + OFF_WSU);
  unsigned short* wsd  = (unsigned short*)(ws + OFF_WSD);
  unsigned short* sh   = (unsigned short*)(ws + OFF_SH);
  unsigned short* hexp = (unsigned short*)(ws + OFF_HEXP);
  int*   ids  = (int*)(ws + OFF_IDS);
  int*   cnt  = (int*)(ws + OFF_META);
  int*   off  = (int*)(ws + OFF_META + 64);
  float* pps  = (float*)(ws + OFF_META + 144);
  float* sig  = (float*)(ws + OFF_SIG);
  float* lg   = (float*)(ws + OFF_LG);
  int*   slotAB = (int*)(ws + OFF_SLOT);
  float* twAB   = (float*)(ws + OFF_TWAB);
  // region reuse (stream-ordered): wgu_bf over sh (dead after sg2),
  // wdn_bf over xbf (dead after eg1), eout over wgu_bf (dead after eg1)
  unsigned short* wgu_bf = (unsigned short*)(ws + OFF_SH);
  unsigned short* wdn_bf = (unsigned short*)(ws + OFF_XBF);
  unsigned short* eout   = (unsigned short*)(ws + OFF_SH);

  hipMemsetAsync(ws + OFF_META, 0, 256, stream);

  // shared weight converts
  {
    int n4;
    n4 = (ISH * HDIM) / 4;
    cvt_kernel<<<(n4 + 255) / 256, 256, 0, stream>>>(WSG, wsg, n4);
    cvt_kernel<<<(n4 + 255) / 256, 256, 0, stream>>>(WSU, wsu, n4);
    n4 = (HDIM * ISH) / 4;
    cvt_kernel<<<(n4 + 255) / 256, 256, 0, stream>>>(WSD, wsd, n4);
  }

  logits_kernel<<<N_TOK / 4, 256, 0, stream>>>(X, GW, SEGW, lg, xbf);
  route_kernel<<<N_TOK / 256, 256, 0, stream>>>(lg, cnt, pps, ids, slotAB, twAB, sig);
  offs_aux_kernel<<<1, 64, 0, stream>>>(cnt, off, pps, Out + (size_t)N_TOK * HDIM);

  // shared expert
  shared_gemm1_kernel<<<dim3(ISH / 64, N_TOK / 128), 256, 0, stream>>>(xbf, wsg, wsu, sh);
  shared_gemm2_kernel<<<dim3(HDIM / 128, N_TOK / 128), 256, 0, stream>>>(sh, wsd, sig, Out);

  // routed experts
  {
    int n4 = (NEXP * 2 * IEXP * HDIM) / 4;
    cvt_kernel<<<(n4 + 255) / 256, 256, 0, stream>>>(WGU, wgu_bf, n4);
  }
  exp_gemm1_kernel<<<dim3(IEXP / 64, N_TOK / 128, NEXP), 256, 0, stream>>>(
      xbf, wgu_bf, ids, cnt, off, hexp);
  {
    int n4 = (NEXP * HDIM * IEXP) / 4;
    cvt_kernel<<<(n4 + 255) / 256, 256, 0, stream>>>(WDN, wdn_bf, n4);
  }
  exp_gemm2_kernel<<<dim3(HDIM / 128, N_TOK / 128, NEXP), 256, 0, stream>>>(
      hexp, wdn_bf, cnt, off, eout);
  combine_kernel<<<N_TOK, 256, 0, stream>>>(eout, slotAB, twAB, off, Out);
}